// Round 4
// baseline (90.152 us; speedup 1.0000x reference)
//
#include <hip/hip_runtime.h>

// GaussianKernelConv: out[b,n,p] = mean_k exp(-||x_bnk - kp_p||^2 / (2 sigma^2))
// B=8, N=8192, K=32, C=3, P=16.
//
// MEASUREMENT ROUND: kernel body identical to R3; launched 3x per call to
// measure the kernel's true duration as (dur_us - 75.5)/2. Writes are
// idempotent so correctness is unaffected; same work every call.

namespace {
constexpr int KN = 32;          // neighbors per point
constexpr int CC = 3;           // coords
constexpr int PP = 16;          // kernel points
constexpr int CHUNK = 8;        // k's per thread
constexpr int TPR = KN / CHUNK; // 4 threads per row
typedef float f32x2 __attribute__((ext_vector_type(2)));
}

__global__ __launch_bounds__(256) void gkc_kernel(
    const float* __restrict__ nb,     // (rows, K, C) f32
    const float* __restrict__ kp,     // (P, C) f32
    const float* __restrict__ sigmap, // scalar
    float* __restrict__ out,          // (rows, P) f32
    int nrows)
{
    const int t = blockIdx.x * 256 + threadIdx.x;
    const int row = t >> 2;
    const int chunk = t & 3;
    if (row >= nrows) return;

    const float sigma = sigmap[0];
    const float s = -1.44269504088896340736f / (2.0f * sigma * sigma); // exp2 scale
    const float W = -2.0f * s;

    // Load this thread's 8 neighbors: 24 contiguous floats = 6x float4.
    const float4* src =
        reinterpret_cast<const float4*>(nb + (size_t)row * (KN * CC) + chunk * (CHUNK * CC));
    float x[24];
#pragma unroll
    for (int i = 0; i < 6; ++i) {
        const float4 v = src[i];
        x[4 * i + 0] = v.x;
        x[4 * i + 1] = v.y;
        x[4 * i + 2] = v.z;
        x[4 * i + 3] = v.w;
    }

    // Packed per-k-pair precompute: Y = (-2s)*x, T0 = s*||x||^2.
    f32x2 Y0[4], Y1[4], Y2[4], T0[4];
#pragma unroll
    for (int j = 0; j < 4; ++j) {
        const float xa0 = x[6 * j + 0], xa1 = x[6 * j + 1], xa2 = x[6 * j + 2];
        const float xb0 = x[6 * j + 3], xb1 = x[6 * j + 4], xb2 = x[6 * j + 5];
        Y0[j] = f32x2{W * xa0, W * xb0};
        Y1[j] = f32x2{W * xa1, W * xb1};
        Y2[j] = f32x2{W * xa2, W * xb2};
        T0[j] = f32x2{s * fmaf(xa0, xa0, fmaf(xa1, xa1, xa2 * xa2)),
                      s * fmaf(xb0, xb0, fmaf(xb1, xb1, xb2 * xb2))};
    }

    float acc[PP];
#pragma unroll
    for (int p = 0; p < PP; ++p) {
        const float ka = kp[3 * p + 0];
        const float kb = kp[3 * p + 1];
        const float kc = kp[3 * p + 2];
        const float cpp = s * fmaf(ka, ka, fmaf(kb, kb, kc * kc)); // s*||kp||^2
        const f32x2 kx2 = {ka, ka}, ky2 = {kb, kb}, kz2 = {kc, kc}, cp2 = {cpp, cpp};

        f32x2 a2 = {0.0f, 0.0f};
#pragma unroll
        for (int j = 0; j < 4; ++j) {
            const f32x2 arg = __builtin_elementwise_fma(Y2[j], kz2,
                              __builtin_elementwise_fma(Y1[j], ky2,
                              __builtin_elementwise_fma(Y0[j], kx2, T0[j] + cp2)));
            a2 += f32x2{__builtin_amdgcn_exp2f(arg.x), __builtin_amdgcn_exp2f(arg.y)};
        }
        acc[p] = a2.x + a2.y;
    }

    // Reduce the 4 per-row lanes (lane bits 0,1): quad-perm DPP shuffles.
#pragma unroll
    for (int p = 0; p < PP; ++p) {
        acc[p] += __shfl_xor(acc[p], 1);
        acc[p] += __shfl_xor(acc[p], 2);
    }

    // Lane `chunk` writes outputs p = 4*chunk .. 4*chunk+3 (static indices only).
    const bool lo = (chunk & 2) == 0;
    const bool even = (chunk & 1) == 0;
    const float o0 = lo ? (even ? acc[0] : acc[4]) : (even ? acc[8] : acc[12]);
    const float o1 = lo ? (even ? acc[1] : acc[5]) : (even ? acc[9] : acc[13]);
    const float o2 = lo ? (even ? acc[2] : acc[6]) : (even ? acc[10] : acc[14]);
    const float o3 = lo ? (even ? acc[3] : acc[7]) : (even ? acc[11] : acc[15]);

    const float inv = 1.0f / (float)KN;
    float4 o;
    o.x = o0 * inv;
    o.y = o1 * inv;
    o.z = o2 * inv;
    o.w = o3 * inv;
    reinterpret_cast<float4*>(out + (size_t)row * PP + chunk * 4)[0] = o;
}

extern "C" void kernel_launch(void* const* d_in, const int* in_sizes, int n_in,
                              void* d_out, int out_size, void* d_ws, size_t ws_size,
                              hipStream_t stream) {
    const float* nb = (const float*)d_in[0];
    const float* kp = (const float*)d_in[1];
    const float* sg = (const float*)d_in[2];
    float* out = (float*)d_out;

    const int nrows = in_sizes[0] / (KN * CC); // B*N = 65536
    const int threads = nrows * TPR;
    const int block = 256;
    const int grid = (threads + block - 1) / block;
    // 3x launch: dur_us delta vs R3 gives the kernel's true duration
    // (T = delta/2). Idempotent -> correctness unchanged.
    for (int rep = 0; rep < 3; ++rep) {
        gkc_kernel<<<grid, block, 0, stream>>>(nb, kp, sg, out, nrows);
    }
}

// Round 7
// 75.598 us; speedup vs baseline: 1.1925x; 1.1925x over previous
//
#include <hip/hip_runtime.h>

// GaussianKernelConv: out[b,n,p] = mean_k exp(-||x_bnk - kp_p||^2 / (2 sigma^2))
// B=8, N=8192, K=32, C=3, P=16.
//
// exp(-d/(2s^2)) = exp2( s*||x||^2 + s*||kp||^2 + (-2s)*(x . kp) ),
//   s = -log2(e)/(2 sigma^2).
//
// R5 (2nd resubmit after acquisition timeouts): occupancy round. 8 threads per
// (b,n) row, 4 k's each -> 524288 threads, 8192 waves = 8 waves/SIMD (2x R3's
// TLP) to hide HBM latency. Each thread: 3x float4 contiguous loads, p-outer
// loop (1 kernel point live at a time), packed f32x2 FMA, 3-stage __shfl_xor
// reduce, float2 store.
// Kernel true time (R4 measurement): 7.3us vs 4.7us memory floor; the rest of
// dur_us (~68us) is harness re-poison overhead (fillBufferAligned rows).

namespace {
constexpr int KN = 32;          // neighbors per point
constexpr int CC = 3;           // coords
constexpr int PP = 16;          // kernel points
constexpr int CHUNK = 4;        // k's per thread
constexpr int TPR = KN / CHUNK; // 8 threads per row
typedef float f32x2 __attribute__((ext_vector_type(2)));
}

__global__ __launch_bounds__(256) void gkc_kernel(
    const float* __restrict__ nb,     // (rows, K, C) f32
    const float* __restrict__ kp,     // (P, C) f32
    const float* __restrict__ sigmap, // scalar
    float* __restrict__ out,          // (rows, P) f32
    int nrows)
{
    const int t = blockIdx.x * 256 + threadIdx.x;
    const int row = t >> 3;
    const int chunk = t & 7;
    if (row >= nrows) return;

    const float sigma = sigmap[0];
    const float s = -1.44269504088896340736f / (2.0f * sigma * sigma); // exp2 scale
    const float W = -2.0f * s;

    // Load this thread's 4 neighbors: 12 contiguous floats = 3x float4
    // (row*384B + chunk*48B -> 16B aligned; wave covers 3KB contiguous).
    const float4* src =
        reinterpret_cast<const float4*>(nb + (size_t)row * (KN * CC) + chunk * (CHUNK * CC));
    float x[12];
#pragma unroll
    for (int i = 0; i < 3; ++i) {
        const float4 v = src[i];
        x[4 * i + 0] = v.x;
        x[4 * i + 1] = v.y;
        x[4 * i + 2] = v.z;
        x[4 * i + 3] = v.w;
    }

    // Packed per-k-pair precompute: Y = (-2s)*x, T0 = s*||x||^2.
    f32x2 Y0[2], Y1[2], Y2[2], T0[2];
#pragma unroll
    for (int j = 0; j < 2; ++j) {
        const float xa0 = x[6 * j + 0], xa1 = x[6 * j + 1], xa2 = x[6 * j + 2];
        const float xb0 = x[6 * j + 3], xb1 = x[6 * j + 4], xb2 = x[6 * j + 5];
        Y0[j] = f32x2{W * xa0, W * xb0};
        Y1[j] = f32x2{W * xa1, W * xb1};
        Y2[j] = f32x2{W * xa2, W * xb2};
        T0[j] = f32x2{s * fmaf(xa0, xa0, fmaf(xa1, xa1, xa2 * xa2)),
                      s * fmaf(xb0, xb0, fmaf(xb1, xb1, xb2 * xb2))};
    }

    float acc[PP];
#pragma unroll
    for (int p = 0; p < PP; ++p) {
        // One kernel point at a time: uniform scalar loads -> SGPRs.
        const float ka = kp[3 * p + 0];
        const float kb = kp[3 * p + 1];
        const float kc = kp[3 * p + 2];
        const float cpp = s * fmaf(ka, ka, fmaf(kb, kb, kc * kc)); // s*||kp||^2
        const f32x2 kx2 = {ka, ka}, ky2 = {kb, kb}, kz2 = {kc, kc}, cp2 = {cpp, cpp};

        f32x2 a2 = {0.0f, 0.0f};
#pragma unroll
        for (int j = 0; j < 2; ++j) {
            const f32x2 arg = __builtin_elementwise_fma(Y2[j], kz2,
                              __builtin_elementwise_fma(Y1[j], ky2,
                              __builtin_elementwise_fma(Y0[j], kx2, T0[j] + cp2)));
            a2 += f32x2{__builtin_amdgcn_exp2f(arg.x), __builtin_amdgcn_exp2f(arg.y)};
        }
        acc[p] = a2.x + a2.y;
    }

    // Reduce the 8 per-row lanes (lane bits 0..2): DPP/swizzle shuffles.
#pragma unroll
    for (int p = 0; p < PP; ++p) {
        acc[p] += __shfl_xor(acc[p], 1);
        acc[p] += __shfl_xor(acc[p], 2);
        acc[p] += __shfl_xor(acc[p], 4);
    }

    // Lane `chunk` writes outputs p = 2*chunk, 2*chunk+1 (static indices only;
    // 3-level cndmask select tree, never runtime array indexing).
    const bool b2 = (chunk & 4) != 0;
    const bool b1 = (chunk & 2) != 0;
    const bool b0 = (chunk & 1) != 0;
    const float e0 = b2 ? (b1 ? (b0 ? acc[14] : acc[12]) : (b0 ? acc[10] : acc[8]))
                        : (b1 ? (b0 ? acc[6]  : acc[4])  : (b0 ? acc[2]  : acc[0]));
    const float e1 = b2 ? (b1 ? (b0 ? acc[15] : acc[13]) : (b0 ? acc[11] : acc[9]))
                        : (b1 ? (b0 ? acc[7]  : acc[5])  : (b0 ? acc[3]  : acc[1]));

    const float inv = 1.0f / (float)KN;
    float2 o;
    o.x = e0 * inv;
    o.y = e1 * inv;
    reinterpret_cast<float2*>(out + (size_t)row * PP + chunk * 2)[0] = o;
}

extern "C" void kernel_launch(void* const* d_in, const int* in_sizes, int n_in,
                              void* d_out, int out_size, void* d_ws, size_t ws_size,
                              hipStream_t stream) {
    const float* nb = (const float*)d_in[0];
    const float* kp = (const float*)d_in[1];
    const float* sg = (const float*)d_in[2];
    float* out = (float*)d_out;

    const int nrows = in_sizes[0] / (KN * CC); // B*N = 65536
    const int threads = nrows * TPR;
    const int block = 256;
    const int grid = (threads + block - 1) / block;
    gkc_kernel<<<grid, block, 0, stream>>>(nb, kp, sg, out, nrows);
}